// Round 7
// baseline (296.430 us; speedup 1.0000x reference)
//
#include <hip/hip_runtime.h>
#include <hip/hip_bf16.h>
#include <stdint.h>

#define N_NODES 100000
#define N_EDGES 600000
#define N_REL 4
#define N_HEADS 4
#define DIM 128
#define HEAD_DIM 32
#define NEG_SLOPE 0.2f

typedef unsigned int uint;
typedef unsigned short ushort;
typedef __attribute__((ext_vector_type(8))) short bf16x8;
typedef __attribute__((ext_vector_type(4))) float f32x4;

__device__ __forceinline__ float bf2f(ushort u) { return __uint_as_float(((uint)u) << 16); }
__device__ __forceinline__ float lo2f(uint u) { return __uint_as_float(u << 16); }
__device__ __forceinline__ float hi2f(uint u) { return __uint_as_float(u & 0xffff0000u); }
__device__ __forceinline__ ushort f2bf(float f) {
    uint u = __float_as_uint(f);
    uint r = (u + 0x7fffu + ((u >> 16) & 1u)) >> 16;   // round-to-nearest-even
    return (ushort)r;
}
__device__ __forceinline__ float lrelu(float v) { return v > 0.f ? v : NEG_SLOPE * v; }

// Inline dtype votes (deterministic and identical in every wave/block since
// they read the same fixed 128 samples).
__device__ __forceinline__ int bf16_plaus(ushort u) {
    int ex = (u >> 7) & 0xFF;
    return (ex >= 100 && ex <= 140) ? 1 : 0;
}
__device__ __forceinline__ int vote_f32(const ushort* p) {   // 1 => fp32
    int lane = threadIdx.x & 63;
    unsigned long long b0 = __ballot(bf16_plaus(p[2 * lane]) != 0);
    unsigned long long b1 = __ballot(bf16_plaus(p[2 * (lane + 64)]) != 0);
    return (__popcll(b0) + __popcll(b1)) < 64;
}
__device__ __forceinline__ int vote_i64(const int* p) {      // 1 => int64
    int lane = threadIdx.x & 63;
    unsigned long long b0 = __ballot(p[2 * lane + 1] != 0);
    unsigned long long b1 = __ballot(p[2 * (lane + 64) + 1] != 0);
    return (__popcll(b0) + __popcll(b1)) < 8;
}

#define XBLKS ((N_NODES * DIM / 8 + 255) / 256)   // 6250
#define HBLKS ((N_EDGES / 4 + 255) / 256)         // 586
#define GBLKS (((N_NODES + 127) / 128) * N_REL)   // 3128
#define NBLKS ((N_NODES + 255) / 256)             // 391

// P0+D2+C1 fused: blocks [0,4) do the one-time W/attn transpose+convert;
// blocks [4, 4+XBLKS) convert x -> bf16; blocks [4+XBLKS, ...) build the
// in-degree histogram (4 edges/thread, vectorized int4 loads). One dispatch.
__global__ __launch_bounds__(256) void k_prep(
    const void* __restrict__ xv, const void* __restrict__ Wv,
    const void* __restrict__ av, const int* __restrict__ ei,
    ushort* __restrict__ x_bf, ushort* __restrict__ Wt_g,
    ushort* __restrict__ at_g, uint* __restrict__ deg)
{
    __shared__ ushort wt[128][136];
    const int tid = threadIdx.x;

    if (blockIdx.x < N_REL) {
        const int r = blockIdx.x;
        const int wf = vote_f32((const ushort*)Wv);
        const int af = vote_f32((const ushort*)av);

        if (wf) {
            const float4* Wg = (const float4*)((const float*)Wv + (size_t)r * DIM * DIM);
            for (int it = 0; it < 16; ++it) {
                int idx = tid + it * 256;              // 4096 float4 = 16384 floats
                int k = idx >> 5, n4 = (idx & 31) * 4;
                float4 v = Wg[idx];
                wt[n4 + 0][k] = f2bf(v.x);
                wt[n4 + 1][k] = f2bf(v.y);
                wt[n4 + 2][k] = f2bf(v.z);
                wt[n4 + 3][k] = f2bf(v.w);
            }
        } else {
            const ushort* Wg = (const ushort*)Wv + (size_t)r * DIM * DIM;
            for (int it = 0; it < 16; ++it) {
                int idx = tid + it * 256;
                int k = idx >> 5, n4 = (idx & 31) * 4;
                const ushort* p = Wg + (size_t)k * DIM + n4;
                wt[n4 + 0][k] = p[0];
                wt[n4 + 1][k] = p[1];
                wt[n4 + 2][k] = p[2];
                wt[n4 + 3][k] = p[3];
            }
        }
        __syncthreads();

        // write W^T rows coalesced as uint4: 128 rows * 17 chunks = 2176
        for (int it = 0; it < 9; ++it) {
            int idx = tid + it * 256;
            if (idx < 2176) {
                int row = idx / 17, c8 = (idx % 17) * 8;
                *(uint4*)(Wt_g + ((size_t)r * 128 + row) * 136 + c8) = *(const uint4*)&wt[row][c8];
            }
        }
        // attn B-matrix: 16 x 136
        for (int it = 0; it < 9; ++it) {
            int idx = tid + it * 256;
            if (idx < 16 * 136) {
                int n = idx / 136, k = idx % 136;
                int h = n & 3, sd = (n >> 2) & 1;
                float v = 0.f;
                if (n < 8 && k < 128) {
                    int d = k - h * 32;
                    if (d >= 0 && d < 32) {
                        size_t ai = ((size_t)(r * N_HEADS + h)) * 64 + (size_t)sd * 32 + d;
                        v = af ? ((const float*)av)[ai] : bf2f(((const ushort*)av)[ai]);
                    }
                }
                at_g[((size_t)r * 16 + n) * 136 + k] = f2bf(v);
            }
        }
    } else if (blockIdx.x < N_REL + XBLKS) {
        const int xf = vote_f32((const ushort*)xv);
        int t = (blockIdx.x - N_REL) * 256 + tid;   // one per 8 elems
        if (t >= N_NODES * DIM / 8) return;
        if (xf) {
            const float4* p = (const float4*)xv + (size_t)t * 2;
            float4 f0 = p[0], f1 = p[1];
            uint4 o;
            o.x = (uint)f2bf(f0.x) | ((uint)f2bf(f0.y) << 16);
            o.y = (uint)f2bf(f0.z) | ((uint)f2bf(f0.w) << 16);
            o.z = (uint)f2bf(f1.x) | ((uint)f2bf(f1.y) << 16);
            o.w = (uint)f2bf(f1.z) | ((uint)f2bf(f1.w) << 16);
            ((uint4*)x_bf)[t] = o;
        } else {
            ((uint4*)x_bf)[t] = ((const uint4*)xv)[t];
        }
    } else {
        // in-degree histogram: 4 edges/thread, vectorized loads
        const int i64e = vote_i64(ei);
        int e0 = ((blockIdx.x - N_REL - XBLKS) * 256 + tid) * 4;
        if (e0 >= N_EDGES) return;
        int d0, d1, d2, d3;
        if (i64e) {
            int4 v0 = *(const int4*)&ei[2 * (N_EDGES + e0)];
            int4 v1 = *(const int4*)&ei[2 * (N_EDGES + e0) + 4];
            d0 = v0.x; d1 = v0.z; d2 = v1.x; d3 = v1.z;
        } else {
            int4 v = *(const int4*)&ei[N_EDGES + e0];
            d0 = v.x; d1 = v.y; d2 = v.z; d3 = v.w;
        }
        atomicAdd(&deg[d0], 1u);
        atomicAdd(&deg[d1], 1u);
        atomicAdd(&deg[d2], 1u);
        atomicAdd(&deg[d3], 1u);
    }
}

// K1 (MFMA) + C2a fused: blocks [0, GBLKS) run the GEMM; blocks
// [GBLKS, GBLKS+NBLKS) run the per-block exclusive scan of deg (depends only
// on the histogram, which completed in the previous dispatch; touches only
// deg/excl/bsum which the GEMM never accesses — no aliasing, no race).
__global__ __launch_bounds__(256) void k_gemm_scan(
    const ushort* __restrict__ x_bf, const ushort* __restrict__ Wt_g,
    const ushort* __restrict__ at_g,
    ushort* __restrict__ x_rel, float* __restrict__ sTab,
    const uint* __restrict__ deg, uint* __restrict__ excl,
    uint* __restrict__ bsum)
{
    __shared__ ushort wt[128][136];   // W^T [n][k]; reused as repack buffer / scan tmp
    __shared__ ushort at[16][136];    // attn as B matrix

    const int tid = threadIdx.x;

    if (blockIdx.x >= GBLKS) {
        // ---- scan1 path ----
        uint* tmp = (uint*)&wt[0][0];
        int sb = blockIdx.x - GBLKS;
        int i = sb * 256 + tid;
        uint v = (i < N_NODES) ? deg[i] : 0u;
        tmp[tid] = v;
        __syncthreads();
        for (int off = 1; off < 256; off <<= 1) {
            uint t = (tid >= off) ? tmp[tid - off] : 0u;
            __syncthreads();
            tmp[tid] += t;
            __syncthreads();
        }
        if (i < N_NODES) excl[i] = tmp[tid] - v;
        if (tid == 255) bsum[sb] = tmp[255];
        return;
    }

    const int wave = tid >> 6, lane = tid & 63;
    const int quad = lane >> 4, l16 = lane & 15;
    const int r = blockIdx.x & 3;            // consecutive blocks share x rows (L2)
    const int n0 = (blockIdx.x >> 2) * 128;

    // stage Wt (2176 uint4) + at (272 uint4) — linear, conflict-free
    {
        const uint4* src  = (const uint4*)(Wt_g + (size_t)r * 128 * 136);
        const uint4* srcA = (const uint4*)(at_g + (size_t)r * 16 * 136);
        uint4* dstL = (uint4*)&wt[0][0];
        uint4* dstA = (uint4*)&at[0][0];
#pragma unroll
        for (int it = 0; it < 10; ++it) {
            int idx = tid + it * 256;
            if (idx < 2176) dstL[idx] = src[idx];
            else if (idx < 2448) dstA[idx - 2176] = srcA[idx - 2176];
        }
    }

    const int rowA0 = n0 + wave * 32 + l16;
    const int rowA1 = rowA0 + 16;
    const size_t rA0 = (size_t)min(rowA0, N_NODES - 1) * DIM;
    const size_t rA1 = (size_t)min(rowA1, N_NODES - 1) * DIM;

    __syncthreads();

    f32x4 acc[2][8];
#pragma unroll
    for (int rt = 0; rt < 2; ++rt)
#pragma unroll
        for (int ct = 0; ct < 8; ++ct) acc[rt][ct] = (f32x4){0.f, 0.f, 0.f, 0.f};

#pragma unroll
    for (int q = 0; q < 4; ++q) {
        const int kb = q * 32 + quad * 8;
        bf16x8 a0 = *(const bf16x8*)(x_bf + rA0 + kb);
        bf16x8 a1 = *(const bf16x8*)(x_bf + rA1 + kb);
#pragma unroll
        for (int ct = 0; ct < 8; ++ct) {
            bf16x8 b = *(const bf16x8*)&wt[ct * 16 + l16][kb];
            acc[0][ct] = __builtin_amdgcn_mfma_f32_16x16x32_bf16(a0, b, acc[0][ct], 0, 0, 0);
            acc[1][ct] = __builtin_amdgcn_mfma_f32_16x16x32_bf16(a1, b, acc[1][ct], 0, 0, 0);
        }
    }
    __syncthreads();

    {
        ushort* rp = &wt[0][0];
#pragma unroll
        for (int rt = 0; rt < 2; ++rt) {
            int rowb = wave * 32 + rt * 16 + quad * 4;
#pragma unroll
            for (int ct = 0; ct < 8; ++ct) {
                int col = ct * 16 + l16;
#pragma unroll
                for (int reg = 0; reg < 4; ++reg)
                    rp[(rowb + reg) * 136 + col] = f2bf(acc[rt][ct][reg]);
            }
        }
    }
    __syncthreads();

    // scores = x_rel · attn  (A = rp rows, B = at)
    {
        const ushort* rp = &wt[0][0];
        f32x4 sacc[2];
        sacc[0] = (f32x4){0.f, 0.f, 0.f, 0.f};
        sacc[1] = (f32x4){0.f, 0.f, 0.f, 0.f};
#pragma unroll
        for (int q = 0; q < 4; ++q) {
            const int kb = q * 32 + quad * 8;
            bf16x8 a0 = *(const bf16x8*)(rp + (wave * 32 + l16) * 136 + kb);
            bf16x8 a1 = *(const bf16x8*)(rp + (wave * 32 + 16 + l16) * 136 + kb);
            bf16x8 bat = *(const bf16x8*)&at[l16][kb];
            sacc[0] = __builtin_amdgcn_mfma_f32_16x16x32_bf16(a0, bat, sacc[0], 0, 0, 0);
            sacc[1] = __builtin_amdgcn_mfma_f32_16x16x32_bf16(a1, bat, sacc[1], 0, 0, 0);
        }
        if (l16 < 8) {
#pragma unroll
            for (int rt = 0; rt < 2; ++rt) {
#pragma unroll
                for (int reg = 0; reg < 4; ++reg) {
                    int node = n0 + wave * 32 + rt * 16 + quad * 4 + reg;
                    if (node < N_NODES)
                        sTab[((size_t)r * N_NODES + node) * 8 + l16] = sacc[rt][reg];
                }
            }
        }
    }

    {
        const ushort* rp = &wt[0][0];
        const size_t rbase = (size_t)r * N_NODES * DIM;
#pragma unroll
        for (int p = 0; p < 8; ++p) {
            int row = p * 16 + (tid >> 4);
            int chunk = tid & 15;
            int node = n0 + row;
            if (node < N_NODES) {
                uint4 v = *(const uint4*)(rp + row * 136 + chunk * 8);
                *(uint4*)(x_rel + rbase + (size_t)node * DIM + chunk * 8) = v;
            }
        }
    }
}

// C2b+C2c fused: each block reduces raw bsum[j < blockIdx.x] itself (<=391
// uints from L2), then start = excl + offset; cursor = start.
__global__ __launch_bounds__(256) void k_scan23(
    const uint* __restrict__ excl, const uint* __restrict__ bsum,
    uint* __restrict__ start, uint* __restrict__ cursor, int nblocks)
{
    __shared__ uint off_s;
    if (threadIdx.x < 64) {
        int lane = threadIdx.x;
        uint acc = 0;
        for (int j = lane; j < blockIdx.x; j += 64) acc += bsum[j];
        for (int o = 32; o; o >>= 1) acc += __shfl_down(acc, o);
        if (lane == 0) off_s = acc;
    }
    __syncthreads();
    uint off = off_s;
    int i = blockIdx.x * 256 + threadIdx.x;
    if (i >= N_NODES) return;
    uint s = excl[i] + off;
    start[i] = s;
    cursor[i] = s;
}

// C3+E1 fused (r5 1-edge/thread version — r6's 4x unroll shrank the grid and
// collapsed occupancy 45%->15%, regressing 53->59us; reverted): fill CSR
// (packed src|rel<<27) AND write per-edge exp(leaky) 4-head vector y at its
// CSR position, so downstream reads are contiguous by position.
__global__ __launch_bounds__(256) void k_fill_y(
    const int* __restrict__ ei, const int* __restrict__ et,
    const float* __restrict__ sTab,
    uint* __restrict__ cursor, uint* __restrict__ csrPack,
    float4* __restrict__ yTab)
{
    const int i64e = vote_i64(ei);
    const int i64t = vote_i64(et);
    int e = blockIdx.x * 256 + threadIdx.x;
    if (e >= N_EDGES) return;
    int s = i64e ? ei[2 * e] : ei[e];
    int d = i64e ? ei[2 * (N_EDGES + e)] : ei[N_EDGES + e];
    int r = i64t ? et[2 * e] : et[e];
    float4 a = *(const float4*)(sTab + ((size_t)r * N_NODES + s) * 8);
    float4 b = *(const float4*)(sTab + ((size_t)r * N_NODES + d) * 8 + 4);
    float4 y;
    y.x = __expf(lrelu(a.x + b.x));
    y.y = __expf(lrelu(a.y + b.y));
    y.z = __expf(lrelu(a.z + b.z));
    y.w = __expf(lrelu(a.w + b.w));
    uint pos = atomicAdd(&cursor[d], 1u);
    csrPack[pos] = (uint)s | ((uint)r << 27);
    yTab[pos] = y;
}

// K4 v6: gather with in-wave denominators (k_norm folded in). Pass 1 walks
// the wave's ~6 contiguous yTab entries (broadcast loads; summation order
// identical to the old k_norm -> bit-identical rs). Pass 2 is the proven
// 8-unrolled pure gather. Zero extra dispatch, dTab deleted.
__global__ __launch_bounds__(256) void k_gather6(
    const uint* __restrict__ start, const uint* __restrict__ deg,
    const uint* __restrict__ csrPack, const float* __restrict__ yTab,
    const uint* __restrict__ x_rel_u, float* __restrict__ out)
{
    const int wv = threadIdx.x >> 6;
    const int dst = blockIdx.x * 4 + wv;
    if (dst >= N_NODES) return;
    const int lane = threadIdx.x & 63;
    const int h = lane >> 4;

    const uint st = start[dst];
    const uint dg = deg[dst];

    float a0 = 0.f, a1 = 0.f;

    if (dg != 0u) {
        const uint last = st + dg - 1u;

        // pass 1: per-rel denominators for this lane's head
        float ds0 = 0.f, ds1 = 0.f, ds2 = 0.f, ds3 = 0.f;
#define DACC(J, VLD) { \
    uint re = pk##J >> 27; \
    float yv = (VLD) ? y##J : 0.f; \
    ds0 += (re == 0) ? yv : 0.f; \
    ds1 += (re == 1) ? yv : 0.f; \
    ds2 += (re == 2) ? yv : 0.f; \
    ds3 += (re == 3) ? yv : 0.f; \
}
        for (uint e0 = 0; e0 < dg; e0 += 4) {
            uint i0 = st + e0;
            uint i1 = (i0 + 1u <= last) ? i0 + 1u : last;
            uint i2 = (i0 + 2u <= last) ? i0 + 2u : last;
            uint i3 = (i0 + 3u <= last) ? i0 + 3u : last;
            uint pk0 = csrPack[i0], pk1 = csrPack[i1];
            uint pk2 = csrPack[i2], pk3 = csrPack[i3];
            float y0 = yTab[(size_t)i0 * 4 + h], y1 = yTab[(size_t)i1 * 4 + h];
            float y2 = yTab[(size_t)i2 * 4 + h], y3 = yTab[(size_t)i3 * 4 + h];
            DACC(0, 1)
            DACC(1, e0 + 1u < dg)
            DACC(2, e0 + 2u < dg)
            DACC(3, e0 + 3u < dg)
        }
#undef DACC
        // rels with no edges: ds stays exactly 0 (exp>0 always) -> rs=0
        float rs0 = (ds0 > 0.f) ? 1.f / ds0 : 0.f;
        float rs1 = (ds1 > 0.f) ? 1.f / ds1 : 0.f;
        float rs2 = (ds2 > 0.f) ? 1.f / ds2 : 0.f;
        float rs3 = (ds3 > 0.f) ? 1.f / ds3 : 0.f;

        // pass 2: 8-unrolled weighted gather (L1-hot pk/y reloads)
#define GACC(J, VLD) { \
    uint re = pk##J >> 27; \
    float rs = (re < 2) ? (re == 0 ? rs0 : rs1) : (re == 2 ? rs2 : rs3); \
    float mw = (VLD) ? y##J * rs : 0.f; \
    a0 = fmaf(mw, lo2f(u##J), a0); a1 = fmaf(mw, hi2f(u##J), a1); \
}
        for (uint e0 = 0; e0 < dg; e0 += 8) {
            uint i0 = st + e0;
            uint i1 = (i0 + 1u <= last) ? i0 + 1u : last;
            uint i2 = (i0 + 2u <= last) ? i0 + 2u : last;
            uint i3 = (i0 + 3u <= last) ? i0 + 3u : last;
            uint i4 = (i0 + 4u <= last) ? i0 + 4u : last;
            uint i5 = (i0 + 5u <= last) ? i0 + 5u : last;
            uint i6 = (i0 + 6u <= last) ? i0 + 6u : last;
            uint i7 = (i0 + 7u <= last) ? i0 + 7u : last;
            uint pk0 = csrPack[i0], pk1 = csrPack[i1];
            uint pk2 = csrPack[i2], pk3 = csrPack[i3];
            uint pk4 = csrPack[i4], pk5 = csrPack[i5];
            uint pk6 = csrPack[i6], pk7 = csrPack[i7];
            float y0 = yTab[(size_t)i0 * 4 + h], y1 = yTab[(size_t)i1 * 4 + h];
            float y2 = yTab[(size_t)i2 * 4 + h], y3 = yTab[(size_t)i3 * 4 + h];
            float y4 = yTab[(size_t)i4 * 4 + h], y5 = yTab[(size_t)i5 * 4 + h];
            float y6 = yTab[(size_t)i6 * 4 + h], y7 = yTab[(size_t)i7 * 4 + h];
            uint u0 = x_rel_u[((size_t)(pk0 >> 27) * N_NODES + (pk0 & 0x07FFFFFFu)) * 64 + lane];
            uint u1 = x_rel_u[((size_t)(pk1 >> 27) * N_NODES + (pk1 & 0x07FFFFFFu)) * 64 + lane];
            uint u2 = x_rel_u[((size_t)(pk2 >> 27) * N_NODES + (pk2 & 0x07FFFFFFu)) * 64 + lane];
            uint u3 = x_rel_u[((size_t)(pk3 >> 27) * N_NODES + (pk3 & 0x07FFFFFFu)) * 64 + lane];
            uint u4 = x_rel_u[((size_t)(pk4 >> 27) * N_NODES + (pk4 & 0x07FFFFFFu)) * 64 + lane];
            uint u5 = x_rel_u[((size_t)(pk5 >> 27) * N_NODES + (pk5 & 0x07FFFFFFu)) * 64 + lane];
            uint u6 = x_rel_u[((size_t)(pk6 >> 27) * N_NODES + (pk6 & 0x07FFFFFFu)) * 64 + lane];
            uint u7 = x_rel_u[((size_t)(pk7 >> 27) * N_NODES + (pk7 & 0x07FFFFFFu)) * 64 + lane];
            GACC(0, 1)
            GACC(1, e0 + 1u < dg)
            GACC(2, e0 + 2u < dg)
            GACC(3, e0 + 3u < dg)
            GACC(4, e0 + 4u < dg)
            GACC(5, e0 + 5u < dg)
            GACC(6, e0 + 6u < dg)
            GACC(7, e0 + 7u < dg)
        }
#undef GACC
    }

    float2 o; o.x = a0; o.y = a1;
    *(float2*)(out + (size_t)dst * DIM + lane * 2) = o;
}

extern "C" void kernel_launch(void* const* d_in, const int* in_sizes, int n_in,
                              void* d_out, int out_size, void* d_ws, size_t ws_size,
                              hipStream_t stream) {
    const void* x    = d_in[0];
    const int*  ei   = (const int*)d_in[1];
    const int*  et   = (const int*)d_in[2];
    const void* W    = d_in[3];
    const void* attn = d_in[4];
    float* out = (float*)d_out;

    char* ws = (char*)d_ws;
    // Wt_g/at_g moved to the free head region (no aliasing: excl is written by
    // the scan blocks INSIDE the gemm dispatch, which also reads Wt_g).
    ushort* Wt_g    = (ushort*)(ws + 0);            // 139,264
    ushort* at_g    = (ushort*)(ws + 139264);       // 17,408
    float*  sTab    = (float*)(ws + 7200256);       // 12,800,000
    ushort* x_rel   = (ushort*)(ws + 20000256);     // 102,400,000
    uint*   deg     = (uint*)(ws + 122400256);      // 400,000
    uint*   excl    = (uint*)(ws + 122800256);      // 400,000
    uint*   bsum    = (uint*)(ws + 123200256);      // 2,048
    uint*   startA  = (uint*)(ws + 123202304);      // 400,000
    uint*   cursor  = (uint*)(ws + 123602304);      // 400,000
    uint*   csrPack = (uint*)(ws + 124002304);      // 2,400,000
    ushort* x_bf    = (ushort*)(ws + 126402304);    // 25,600,000
    // yTab aliases the x_bf region (x_bf dead after k_gemm_scan).
    float4* yTab    = (float4*)(ws + 126402304);    // 9,600,000

    hipMemsetAsync(deg, 0, 400000, stream);

    k_prep<<<N_REL + XBLKS + HBLKS, 256, 0, stream>>>(
        x, W, attn, ei, x_bf, Wt_g, at_g, deg);

    k_gemm_scan<<<GBLKS + NBLKS, 256, 0, stream>>>(x_bf, Wt_g, at_g,
                                                   x_rel, sTab, deg, excl, bsum);

    k_scan23<<<NBLKS, 256, 0, stream>>>(excl, bsum, startA, cursor, NBLKS);
    k_fill_y<<<(N_EDGES + 255) / 256, 256, 0, stream>>>(ei, et, sTab, cursor,
                                                        csrPack, yTab);
    k_gather6<<<(N_NODES + 3) / 4, 256, 0, stream>>>(startA, deg, csrPack,
                                                     (const float*)yTab,
                                                     (const uint*)x_rel, out);
}

// Round 8
// 274.810 us; speedup vs baseline: 1.0787x; 1.0787x over previous
//
#include <hip/hip_runtime.h>
#include <hip/hip_bf16.h>
#include <stdint.h>

#define N_NODES 100000
#define N_EDGES 600000
#define N_REL 4
#define N_HEADS 4
#define DIM 128
#define HEAD_DIM 32
#define NEG_SLOPE 0.2f

typedef unsigned int uint;
typedef unsigned short ushort;
typedef __attribute__((ext_vector_type(8))) short bf16x8;
typedef __attribute__((ext_vector_type(4))) float f32x4;

__device__ __forceinline__ float bf2f(ushort u) { return __uint_as_float(((uint)u) << 16); }
__device__ __forceinline__ float lo2f(uint u) { return __uint_as_float(u << 16); }
__device__ __forceinline__ float hi2f(uint u) { return __uint_as_float(u & 0xffff0000u); }
__device__ __forceinline__ ushort f2bf(float f) {
    uint u = __float_as_uint(f);
    uint r = (u + 0x7fffu + ((u >> 16) & 1u)) >> 16;   // round-to-nearest-even
    return (ushort)r;
}
__device__ __forceinline__ float lrelu(float v) { return v > 0.f ? v : NEG_SLOPE * v; }

// Inline dtype votes (deterministic and identical in every wave/block since
// they read the same fixed 128 samples).
__device__ __forceinline__ int bf16_plaus(ushort u) {
    int ex = (u >> 7) & 0xFF;
    return (ex >= 100 && ex <= 140) ? 1 : 0;
}
__device__ __forceinline__ int vote_f32(const ushort* p) {   // 1 => fp32
    int lane = threadIdx.x & 63;
    unsigned long long b0 = __ballot(bf16_plaus(p[2 * lane]) != 0);
    unsigned long long b1 = __ballot(bf16_plaus(p[2 * (lane + 64)]) != 0);
    return (__popcll(b0) + __popcll(b1)) < 64;
}
__device__ __forceinline__ int vote_i64(const int* p) {      // 1 => int64
    int lane = threadIdx.x & 63;
    unsigned long long b0 = __ballot(p[2 * lane + 1] != 0);
    unsigned long long b1 = __ballot(p[2 * (lane + 64) + 1] != 0);
    return (__popcll(b0) + __popcll(b1)) < 8;
}

#define XBLKS ((N_NODES * DIM / 8 + 255) / 256)   // 6250
#define HBLKS ((N_EDGES / 4 + 255) / 256)         // 586
#define GBLKS (((N_NODES + 127) / 128) * N_REL)   // 3128
#define NBLKS ((N_NODES + 255) / 256)             // 391

// P0+D2+C1 fused: blocks [0,4) do the one-time W/attn transpose+convert;
// blocks [4, 4+XBLKS) convert x -> bf16; blocks [4+XBLKS, ...) build the
// in-degree histogram (4 edges/thread, vectorized int4 loads). One dispatch.
__global__ __launch_bounds__(256) void k_prep(
    const void* __restrict__ xv, const void* __restrict__ Wv,
    const void* __restrict__ av, const int* __restrict__ ei,
    ushort* __restrict__ x_bf, ushort* __restrict__ Wt_g,
    ushort* __restrict__ at_g, uint* __restrict__ deg)
{
    __shared__ ushort wt[128][136];
    const int tid = threadIdx.x;

    if (blockIdx.x < N_REL) {
        const int r = blockIdx.x;
        const int wf = vote_f32((const ushort*)Wv);
        const int af = vote_f32((const ushort*)av);

        if (wf) {
            const float4* Wg = (const float4*)((const float*)Wv + (size_t)r * DIM * DIM);
            for (int it = 0; it < 16; ++it) {
                int idx = tid + it * 256;              // 4096 float4 = 16384 floats
                int k = idx >> 5, n4 = (idx & 31) * 4;
                float4 v = Wg[idx];
                wt[n4 + 0][k] = f2bf(v.x);
                wt[n4 + 1][k] = f2bf(v.y);
                wt[n4 + 2][k] = f2bf(v.z);
                wt[n4 + 3][k] = f2bf(v.w);
            }
        } else {
            const ushort* Wg = (const ushort*)Wv + (size_t)r * DIM * DIM;
            for (int it = 0; it < 16; ++it) {
                int idx = tid + it * 256;
                int k = idx >> 5, n4 = (idx & 31) * 4;
                const ushort* p = Wg + (size_t)k * DIM + n4;
                wt[n4 + 0][k] = p[0];
                wt[n4 + 1][k] = p[1];
                wt[n4 + 2][k] = p[2];
                wt[n4 + 3][k] = p[3];
            }
        }
        __syncthreads();

        // write W^T rows coalesced as uint4: 128 rows * 17 chunks = 2176
        for (int it = 0; it < 9; ++it) {
            int idx = tid + it * 256;
            if (idx < 2176) {
                int row = idx / 17, c8 = (idx % 17) * 8;
                *(uint4*)(Wt_g + ((size_t)r * 128 + row) * 136 + c8) = *(const uint4*)&wt[row][c8];
            }
        }
        // attn B-matrix: 16 x 136
        for (int it = 0; it < 9; ++it) {
            int idx = tid + it * 256;
            if (idx < 16 * 136) {
                int n = idx / 136, k = idx % 136;
                int h = n & 3, sd = (n >> 2) & 1;
                float v = 0.f;
                if (n < 8 && k < 128) {
                    int d = k - h * 32;
                    if (d >= 0 && d < 32) {
                        size_t ai = ((size_t)(r * N_HEADS + h)) * 64 + (size_t)sd * 32 + d;
                        v = af ? ((const float*)av)[ai] : bf2f(((const ushort*)av)[ai]);
                    }
                }
                at_g[((size_t)r * 16 + n) * 136 + k] = f2bf(v);
            }
        }
    } else if (blockIdx.x < N_REL + XBLKS) {
        const int xf = vote_f32((const ushort*)xv);
        int t = (blockIdx.x - N_REL) * 256 + tid;   // one per 8 elems
        if (t >= N_NODES * DIM / 8) return;
        if (xf) {
            const float4* p = (const float4*)xv + (size_t)t * 2;
            float4 f0 = p[0], f1 = p[1];
            uint4 o;
            o.x = (uint)f2bf(f0.x) | ((uint)f2bf(f0.y) << 16);
            o.y = (uint)f2bf(f0.z) | ((uint)f2bf(f0.w) << 16);
            o.z = (uint)f2bf(f1.x) | ((uint)f2bf(f1.y) << 16);
            o.w = (uint)f2bf(f1.z) | ((uint)f2bf(f1.w) << 16);
            ((uint4*)x_bf)[t] = o;
        } else {
            ((uint4*)x_bf)[t] = ((const uint4*)xv)[t];
        }
    } else {
        // in-degree histogram: 4 edges/thread, vectorized loads
        const int i64e = vote_i64(ei);
        int e0 = ((blockIdx.x - N_REL - XBLKS) * 256 + tid) * 4;
        if (e0 >= N_EDGES) return;
        int d0, d1, d2, d3;
        if (i64e) {
            int4 v0 = *(const int4*)&ei[2 * (N_EDGES + e0)];
            int4 v1 = *(const int4*)&ei[2 * (N_EDGES + e0) + 4];
            d0 = v0.x; d1 = v0.z; d2 = v1.x; d3 = v1.z;
        } else {
            int4 v = *(const int4*)&ei[N_EDGES + e0];
            d0 = v.x; d1 = v.y; d2 = v.z; d3 = v.w;
        }
        atomicAdd(&deg[d0], 1u);
        atomicAdd(&deg[d1], 1u);
        atomicAdd(&deg[d2], 1u);
        atomicAdd(&deg[d3], 1u);
    }
}

// K1 (MFMA) + C2a fused: blocks [0, GBLKS) run the GEMM; blocks
// [GBLKS, GBLKS+NBLKS) run the per-block exclusive scan of deg (depends only
// on the histogram, which completed in the previous dispatch; touches only
// deg/excl/bsum which the GEMM never accesses — no aliasing, no race).
__global__ __launch_bounds__(256) void k_gemm_scan(
    const ushort* __restrict__ x_bf, const ushort* __restrict__ Wt_g,
    const ushort* __restrict__ at_g,
    ushort* __restrict__ x_rel, float* __restrict__ sTab,
    const uint* __restrict__ deg, uint* __restrict__ excl,
    uint* __restrict__ bsum)
{
    __shared__ ushort wt[128][136];   // W^T [n][k]; reused as repack buffer / scan tmp
    __shared__ ushort at[16][136];    // attn as B matrix

    const int tid = threadIdx.x;

    if (blockIdx.x >= GBLKS) {
        // ---- scan1 path ----
        uint* tmp = (uint*)&wt[0][0];
        int sb = blockIdx.x - GBLKS;
        int i = sb * 256 + tid;
        uint v = (i < N_NODES) ? deg[i] : 0u;
        tmp[tid] = v;
        __syncthreads();
        for (int off = 1; off < 256; off <<= 1) {
            uint t = (tid >= off) ? tmp[tid - off] : 0u;
            __syncthreads();
            tmp[tid] += t;
            __syncthreads();
        }
        if (i < N_NODES) excl[i] = tmp[tid] - v;
        if (tid == 255) bsum[sb] = tmp[255];
        return;
    }

    const int wave = tid >> 6, lane = tid & 63;
    const int quad = lane >> 4, l16 = lane & 15;
    const int r = blockIdx.x & 3;            // consecutive blocks share x rows (L2)
    const int n0 = (blockIdx.x >> 2) * 128;

    // stage Wt (2176 uint4) + at (272 uint4) — linear, conflict-free
    {
        const uint4* src  = (const uint4*)(Wt_g + (size_t)r * 128 * 136);
        const uint4* srcA = (const uint4*)(at_g + (size_t)r * 16 * 136);
        uint4* dstL = (uint4*)&wt[0][0];
        uint4* dstA = (uint4*)&at[0][0];
#pragma unroll
        for (int it = 0; it < 10; ++it) {
            int idx = tid + it * 256;
            if (idx < 2176) dstL[idx] = src[idx];
            else if (idx < 2448) dstA[idx - 2176] = srcA[idx - 2176];
        }
    }

    const int rowA0 = n0 + wave * 32 + l16;
    const int rowA1 = rowA0 + 16;
    const size_t rA0 = (size_t)min(rowA0, N_NODES - 1) * DIM;
    const size_t rA1 = (size_t)min(rowA1, N_NODES - 1) * DIM;

    __syncthreads();

    f32x4 acc[2][8];
#pragma unroll
    for (int rt = 0; rt < 2; ++rt)
#pragma unroll
        for (int ct = 0; ct < 8; ++ct) acc[rt][ct] = (f32x4){0.f, 0.f, 0.f, 0.f};

#pragma unroll
    for (int q = 0; q < 4; ++q) {
        const int kb = q * 32 + quad * 8;
        bf16x8 a0 = *(const bf16x8*)(x_bf + rA0 + kb);
        bf16x8 a1 = *(const bf16x8*)(x_bf + rA1 + kb);
#pragma unroll
        for (int ct = 0; ct < 8; ++ct) {
            bf16x8 b = *(const bf16x8*)&wt[ct * 16 + l16][kb];
            acc[0][ct] = __builtin_amdgcn_mfma_f32_16x16x32_bf16(a0, b, acc[0][ct], 0, 0, 0);
            acc[1][ct] = __builtin_amdgcn_mfma_f32_16x16x32_bf16(a1, b, acc[1][ct], 0, 0, 0);
        }
    }
    __syncthreads();

    {
        ushort* rp = &wt[0][0];
#pragma unroll
        for (int rt = 0; rt < 2; ++rt) {
            int rowb = wave * 32 + rt * 16 + quad * 4;
#pragma unroll
            for (int ct = 0; ct < 8; ++ct) {
                int col = ct * 16 + l16;
#pragma unroll
                for (int reg = 0; reg < 4; ++reg)
                    rp[(rowb + reg) * 136 + col] = f2bf(acc[rt][ct][reg]);
            }
        }
    }
    __syncthreads();

    // scores = x_rel · attn  (A = rp rows, B = at)
    {
        const ushort* rp = &wt[0][0];
        f32x4 sacc[2];
        sacc[0] = (f32x4){0.f, 0.f, 0.f, 0.f};
        sacc[1] = (f32x4){0.f, 0.f, 0.f, 0.f};
#pragma unroll
        for (int q = 0; q < 4; ++q) {
            const int kb = q * 32 + quad * 8;
            bf16x8 a0 = *(const bf16x8*)(rp + (wave * 32 + l16) * 136 + kb);
            bf16x8 a1 = *(const bf16x8*)(rp + (wave * 32 + 16 + l16) * 136 + kb);
            bf16x8 bat = *(const bf16x8*)&at[l16][kb];
            sacc[0] = __builtin_amdgcn_mfma_f32_16x16x32_bf16(a0, bat, sacc[0], 0, 0, 0);
            sacc[1] = __builtin_amdgcn_mfma_f32_16x16x32_bf16(a1, bat, sacc[1], 0, 0, 0);
        }
        if (l16 < 8) {
#pragma unroll
            for (int rt = 0; rt < 2; ++rt) {
#pragma unroll
                for (int reg = 0; reg < 4; ++reg) {
                    int node = n0 + wave * 32 + rt * 16 + quad * 4 + reg;
                    if (node < N_NODES)
                        sTab[((size_t)r * N_NODES + node) * 8 + l16] = sacc[rt][reg];
                }
            }
        }
    }

    {
        const ushort* rp = &wt[0][0];
        const size_t rbase = (size_t)r * N_NODES * DIM;
#pragma unroll
        for (int p = 0; p < 8; ++p) {
            int row = p * 16 + (tid >> 4);
            int chunk = tid & 15;
            int node = n0 + row;
            if (node < N_NODES) {
                uint4 v = *(const uint4*)(rp + row * 136 + chunk * 8);
                *(uint4*)(x_rel + rbase + (size_t)node * DIM + chunk * 8) = v;
            }
        }
    }
}

// C2b+C2c fused: each block reduces raw bsum[j < blockIdx.x] itself (<=391
// uints from L2), then start = excl + offset; cursor = start.
__global__ __launch_bounds__(256) void k_scan23(
    const uint* __restrict__ excl, const uint* __restrict__ bsum,
    uint* __restrict__ start, uint* __restrict__ cursor, int nblocks)
{
    __shared__ uint off_s;
    if (threadIdx.x < 64) {
        int lane = threadIdx.x;
        uint acc = 0;
        for (int j = lane; j < blockIdx.x; j += 64) acc += bsum[j];
        for (int o = 32; o; o >>= 1) acc += __shfl_down(acc, o);
        if (lane == 0) off_s = acc;
    }
    __syncthreads();
    uint off = off_s;
    int i = blockIdx.x * 256 + threadIdx.x;
    if (i >= N_NODES) return;
    uint s = excl[i] + off;
    start[i] = s;
    cursor[i] = s;
}

// C3+E1 fused (1-edge/thread — proven best occupancy): fill CSR AND write
// per-edge exp(leaky) 4-head vector y at its CSR position. pk payload is now
// the x_rel ROW INDEX (r*N_NODES+src, 19 bits) | rel<<27 — saves a 64-bit
// mad per row-address in the gather.
__global__ __launch_bounds__(256) void k_fill_y(
    const int* __restrict__ ei, const int* __restrict__ et,
    const float* __restrict__ sTab,
    uint* __restrict__ cursor, uint* __restrict__ csrPack,
    float4* __restrict__ yTab)
{
    const int i64e = vote_i64(ei);
    const int i64t = vote_i64(et);
    int e = blockIdx.x * 256 + threadIdx.x;
    if (e >= N_EDGES) return;
    int s = i64e ? ei[2 * e] : ei[e];
    int d = i64e ? ei[2 * (N_EDGES + e)] : ei[N_EDGES + e];
    int r = i64t ? et[2 * e] : et[e];
    uint row = (uint)r * N_NODES + (uint)s;          // x_rel/sTab row index
    float4 a = *(const float4*)(sTab + (size_t)row * 8);
    float4 b = *(const float4*)(sTab + ((size_t)r * N_NODES + d) * 8 + 4);
    float4 y;
    y.x = __expf(lrelu(a.x + b.x));
    y.y = __expf(lrelu(a.y + b.y));
    y.z = __expf(lrelu(a.z + b.z));
    y.w = __expf(lrelu(a.w + b.w));
    uint pos = atomicAdd(&cursor[d], 1u);
    csrPack[pos] = row | ((uint)r << 27);
    yTab[pos] = y;
}

// N1: per-(rel,dst,head) reciprocal denominators. One THREAD per dst (not
// one wave — r7's in-wave version was 64x redundant VALU, 89% VALUBusy);
// one streaming pass over the contiguous yTab segment, 4x ILP.
__global__ __launch_bounds__(256) void k_norm(
    const uint* __restrict__ start, const uint* __restrict__ deg,
    const uint* __restrict__ csrPack, const float4* __restrict__ yTab,
    float4* __restrict__ dTab)
{
    int dst = blockIdx.x * 256 + threadIdx.x;
    if (dst >= N_NODES) return;
    const uint st = start[dst];
    const uint dg = deg[dst];

    float4 s0 = {0.f, 0.f, 0.f, 0.f}, s1 = s0, s2 = s0, s3 = s0;

#define NACC(J, VLD) { \
    uint re = pk##J >> 27; \
    float vm = (VLD) ? 1.f : 0.f; \
    float yx = y##J.x * vm, yy = y##J.y * vm, yz = y##J.z * vm, yw = y##J.w * vm; \
    s0.x += (re == 0) ? yx : 0.f; s0.y += (re == 0) ? yy : 0.f; \
    s0.z += (re == 0) ? yz : 0.f; s0.w += (re == 0) ? yw : 0.f; \
    s1.x += (re == 1) ? yx : 0.f; s1.y += (re == 1) ? yy : 0.f; \
    s1.z += (re == 1) ? yz : 0.f; s1.w += (re == 1) ? yw : 0.f; \
    s2.x += (re == 2) ? yx : 0.f; s2.y += (re == 2) ? yy : 0.f; \
    s2.z += (re == 2) ? yz : 0.f; s2.w += (re == 2) ? yw : 0.f; \
    s3.x += (re == 3) ? yx : 0.f; s3.y += (re == 3) ? yy : 0.f; \
    s3.z += (re == 3) ? yz : 0.f; s3.w += (re == 3) ? yw : 0.f; \
}
    if (dg != 0u) {
        const uint last = st + dg - 1u;
        for (uint e0 = 0; e0 < dg; e0 += 4) {
            uint i0 = st + e0;
            uint i1 = (i0 + 1u <= last) ? i0 + 1u : last;
            uint i2 = (i0 + 2u <= last) ? i0 + 2u : last;
            uint i3 = (i0 + 3u <= last) ? i0 + 3u : last;
            uint pk0 = csrPack[i0], pk1 = csrPack[i1];
            uint pk2 = csrPack[i2], pk3 = csrPack[i3];
            float4 y0 = yTab[i0], y1 = yTab[i1], y2 = yTab[i2], y3 = yTab[i3];
            NACC(0, 1)
            NACC(1, e0 + 1u < dg)
            NACC(2, e0 + 2u < dg)
            NACC(3, e0 + 3u < dg)
        }
    }
#undef NACC

    // write reciprocals; rels with no edges stay exactly 0 (exp>0 always)
    float4 r0, r1, r2, r3;
    r0.x = s0.x > 0.f ? 1.f / s0.x : 0.f; r0.y = s0.y > 0.f ? 1.f / s0.y : 0.f;
    r0.z = s0.z > 0.f ? 1.f / s0.z : 0.f; r0.w = s0.w > 0.f ? 1.f / s0.w : 0.f;
    r1.x = s1.x > 0.f ? 1.f / s1.x : 0.f; r1.y = s1.y > 0.f ? 1.f / s1.y : 0.f;
    r1.z = s1.z > 0.f ? 1.f / s1.z : 0.f; r1.w = s1.w > 0.f ? 1.f / s1.w : 0.f;
    r2.x = s2.x > 0.f ? 1.f / s2.x : 0.f; r2.y = s2.y > 0.f ? 1.f / s2.y : 0.f;
    r2.z = s2.z > 0.f ? 1.f / s2.z : 0.f; r2.w = s2.w > 0.f ? 1.f / s2.w : 0.f;
    r3.x = s3.x > 0.f ? 1.f / s3.x : 0.f; r3.y = s3.y > 0.f ? 1.f / s3.y : 0.f;
    r3.z = s3.z > 0.f ? 1.f / s3.z : 0.f; r3.w = s3.w > 0.f ? 1.f / s3.w : 0.f;
    dTab[(size_t)0 * N_NODES + dst] = r0;
    dTab[(size_t)1 * N_NODES + dst] = r1;
    dTab[(size_t)2 * N_NODES + dst] = r2;
    dTab[(size_t)3 * N_NODES + dst] = r3;
}

// K4 v7: pure weighted gather (r5's proven structure), 8x unrolled, with:
//  - st/dg via readfirstlane (wave-uniform) -> clamp math + csrPack/yTab
//    addressing on the SALU / scalar path;
//  - pk payload is the x_rel row index directly (no 64-bit mad per row).
__global__ __launch_bounds__(256) void k_gather7(
    const uint* __restrict__ start, const uint* __restrict__ deg,
    const uint* __restrict__ csrPack, const float* __restrict__ dTab,
    const float* __restrict__ yTab,
    const uint* __restrict__ x_rel_u, float* __restrict__ out)
{
    const int wv = threadIdx.x >> 6;
    const int dst = blockIdx.x * 4 + wv;
    if (dst >= N_NODES) return;
    const int lane = threadIdx.x & 63;
    const int h = lane >> 4;

    const uint st = (uint)__builtin_amdgcn_readfirstlane((int)start[dst]);
    const uint dg = (uint)__builtin_amdgcn_readfirstlane((int)deg[dst]);

    float rs0 = dTab[((size_t)0 * N_NODES + dst) * 4 + h];
    float rs1 = dTab[((size_t)1 * N_NODES + dst) * 4 + h];
    float rs2 = dTab[((size_t)2 * N_NODES + dst) * 4 + h];
    float rs3 = dTab[((size_t)3 * N_NODES + dst) * 4 + h];

    float a0 = 0.f, a1 = 0.f;

#define GACC(J, VLD) { \
    uint re = pk##J >> 27; \
    float rs = (re < 2) ? (re == 0 ? rs0 : rs1) : (re == 2 ? rs2 : rs3); \
    float mw = (VLD) ? y##J * rs : 0.f; \
    a0 = fmaf(mw, lo2f(u##J), a0); a1 = fmaf(mw, hi2f(u##J), a1); \
}
    if (dg != 0u) {
        const uint last = st + dg - 1u;
        for (uint e0 = 0; e0 < dg; e0 += 8) {
            uint i0 = st + e0;
            uint i1 = (i0 + 1u <= last) ? i0 + 1u : last;
            uint i2 = (i0 + 2u <= last) ? i0 + 2u : last;
            uint i3 = (i0 + 3u <= last) ? i0 + 3u : last;
            uint i4 = (i0 + 4u <= last) ? i0 + 4u : last;
            uint i5 = (i0 + 5u <= last) ? i0 + 5u : last;
            uint i6 = (i0 + 6u <= last) ? i0 + 6u : last;
            uint i7 = (i0 + 7u <= last) ? i0 + 7u : last;
            uint pk0 = csrPack[i0], pk1 = csrPack[i1];
            uint pk2 = csrPack[i2], pk3 = csrPack[i3];
            uint pk4 = csrPack[i4], pk5 = csrPack[i5];
            uint pk6 = csrPack[i6], pk7 = csrPack[i7];
            float y0 = yTab[(size_t)i0 * 4 + h], y1 = yTab[(size_t)i1 * 4 + h];
            float y2 = yTab[(size_t)i2 * 4 + h], y3 = yTab[(size_t)i3 * 4 + h];
            float y4 = yTab[(size_t)i4 * 4 + h], y5 = yTab[(size_t)i5 * 4 + h];
            float y6 = yTab[(size_t)i6 * 4 + h], y7 = yTab[(size_t)i7 * 4 + h];
            uint u0 = x_rel_u[(size_t)(pk0 & 0x07FFFFFFu) * 64 + lane];
            uint u1 = x_rel_u[(size_t)(pk1 & 0x07FFFFFFu) * 64 + lane];
            uint u2 = x_rel_u[(size_t)(pk2 & 0x07FFFFFFu) * 64 + lane];
            uint u3 = x_rel_u[(size_t)(pk3 & 0x07FFFFFFu) * 64 + lane];
            uint u4 = x_rel_u[(size_t)(pk4 & 0x07FFFFFFu) * 64 + lane];
            uint u5 = x_rel_u[(size_t)(pk5 & 0x07FFFFFFu) * 64 + lane];
            uint u6 = x_rel_u[(size_t)(pk6 & 0x07FFFFFFu) * 64 + lane];
            uint u7 = x_rel_u[(size_t)(pk7 & 0x07FFFFFFu) * 64 + lane];
            GACC(0, 1)
            GACC(1, e0 + 1u < dg)
            GACC(2, e0 + 2u < dg)
            GACC(3, e0 + 3u < dg)
            GACC(4, e0 + 4u < dg)
            GACC(5, e0 + 5u < dg)
            GACC(6, e0 + 6u < dg)
            GACC(7, e0 + 7u < dg)
        }
    }
#undef GACC

    float2 o; o.x = a0; o.y = a1;
    *(float2*)(out + (size_t)dst * DIM + lane * 2) = o;
}

extern "C" void kernel_launch(void* const* d_in, const int* in_sizes, int n_in,
                              void* d_out, int out_size, void* d_ws, size_t ws_size,
                              hipStream_t stream) {
    const void* x    = d_in[0];
    const int*  ei   = (const int*)d_in[1];
    const int*  et   = (const int*)d_in[2];
    const void* W    = d_in[3];
    const void* attn = d_in[4];
    float* out = (float*)d_out;

    char* ws = (char*)d_ws;
    ushort* Wt_g    = (ushort*)(ws + 0);            // 139,264
    ushort* at_g    = (ushort*)(ws + 139264);       // 17,408
    float*  sTab    = (float*)(ws + 7200256);       // 12,800,000
    ushort* x_rel   = (ushort*)(ws + 20000256);     // 102,400,000
    uint*   deg     = (uint*)(ws + 122400256);      // 400,000
    uint*   excl    = (uint*)(ws + 122800256);      // 400,000
    uint*   bsum    = (uint*)(ws + 123200256);      // 2,048
    uint*   startA  = (uint*)(ws + 123202304);      // 400,000
    uint*   cursor  = (uint*)(ws + 123602304);      // 400,000
    uint*   csrPack = (uint*)(ws + 124002304);      // 2,400,000
    ushort* x_bf    = (ushort*)(ws + 126402304);    // 25,600,000
    // dTab/yTab alias the x_bf region (x_bf dead after k_gemm_scan).
    float4* dTab    = (float4*)(ws + 126402304);    // 6,400,000
    float4* yTab    = (float4*)(ws + 132802304);    // 9,600,000

    hipMemsetAsync(deg, 0, 400000, stream);

    k_prep<<<N_REL + XBLKS + HBLKS, 256, 0, stream>>>(
        x, W, attn, ei, x_bf, Wt_g, at_g, deg);

    k_gemm_scan<<<GBLKS + NBLKS, 256, 0, stream>>>(x_bf, Wt_g, at_g,
                                                   x_rel, sTab, deg, excl, bsum);

    k_scan23<<<NBLKS, 256, 0, stream>>>(excl, bsum, startA, cursor, NBLKS);
    k_fill_y<<<(N_EDGES + 255) / 256, 256, 0, stream>>>(ei, et, sTab, cursor,
                                                        csrPack, yTab);
    k_norm<<<NBLKS, 256, 0, stream>>>(startA, deg, csrPack, yTab, dTab);
    k_gather7<<<(N_NODES + 3) / 4, 256, 0, stream>>>(startA, deg, csrPack,
                                                     (const float*)dTab,
                                                     (const float*)yTab,
                                                     (const uint*)x_rel, out);
}